// Round 4
// baseline (151.077 us; speedup 1.0000x reference)
//
#include <hip/hip_runtime.h>
#include <hip/hip_fp16.h>

// ---------------------------------------------------------------------------
// TFN-lite layer, MI355X, round 10. Three graph nodes:
//   memset(cnt) -> prep_all(table build + geometry scatter) -> tfn_node.
//
//  R10 changes vs R9 (142.9 us; tfn_node 53.5 us, latency-bound: -26% VALU
//  ops in R9 bought only -5% time):
//  * tfn_node software pipeline: T-row loads issued ONE FULL ROUND ahead
//    into ping-pong register sets TA/TB (all names static -- no runtime
//    indexing -> no scratch). While round rd computes from its set, the
//    loads for rd+2 are in flight with ~a full round of compute to hide
//    under. j0 clamped to [0,TBL-2] so speculative loads on masked/garbage
//    slots are in-bounds; accumulation still guarded by slot<kc; valid-lane
//    math bit-identical to R9.
//  * Costs ~+80 VGPR (two 10xhalf8 sets) -> ~140; 3 waves/SIMD is at the
//    measured residency anyway -- the pipeline removes the need for TLP.
// ---------------------------------------------------------------------------

#define INV_S3  0.5773502691896258f   // 1/sqrt(3)
#define A0S     0.1767766952966369f   // 1/sqrt(32)
#define A1S     0.27386127875258306f  // sqrt(3)/sqrt(40)
#define S15     3.872983346207417f    // sqrt(15)
#define S5      2.23606797749979f     // sqrt(5)
#define INV_S10 0.31622776601683794f  // 1/sqrt(10)   (cg121 normalized)
#define INV_S30 0.18257418583505536f  // 1/sqrt(30)

#define TBL   2048
#define DMAX  8.0f
#define CAP   64

typedef _Float16 half8 __attribute__((ext_vector_type(8)));
typedef _Float16 half2v __attribute__((ext_vector_type(2)));

// ---------------------------------------------------------------------------
// K1: blocks 0..511 build table rows (one wave per row j); all 2048 blocks
// then grid-stride the geometry scatter.  (unchanged from R9)
__global__ __launch_bounds__(256) void prep_all(
    const float* __restrict__ W1, const float* __restrict__ W2,
    const int* __restrict__ ei, const float* __restrict__ pos,
    _Float16* __restrict__ T, int* __restrict__ cnt,
    float4* __restrict__ srec, int E) {

    __shared__ float hs[4][64];
    int tid = threadIdx.x;
    int wv = tid >> 6, lane = tid & 63;
    int j = blockIdx.x * 4 + wv;

    float hv = 0.f;
    if (j < TBL) {
        float d = (float)j * (DMAX / (float)(TBL - 1));
        float acc = 0.f;
#pragma unroll
        for (int i = 0; i < 16; ++i) {
            float t = d - (float)i * (1.0f / 3.0f);
            float r = __expf(-4.5f * t * t);
            acc = fmaf(r, W1[i * 64 + lane], acc);
        }
        hv = fmaxf(acc, 0.f) * 0.25f;   // /sqrt(16)
    }
    hs[wv][lane] = hv;
    __syncthreads();

    if (j < TBL) {
        int u = lane >> 3, wo = lane & 7;
        int b0 = u * 16 + wo;
        int b4 = 512 + u * 8 + wo;
        float a0 = 0.f, a1 = 0.f, a2 = 0.f, a3 = 0.f, a4 = 0.f;
#pragma unroll 4
        for (int k = 0; k < 64; ++k) {
            float hk = hs[wv][k];
            const float* Wk = W2 + k * 576;
            a0 = fmaf(hk, Wk[b0]       + Wk[b0 + 8],       a0);
            a1 = fmaf(hk, Wk[128 + b0] + Wk[128 + b0 + 8], a1);
            a2 = fmaf(hk, Wk[256 + b0] + Wk[256 + b0 + 8], a2);
            a3 = fmaf(hk, Wk[384 + b0] + Wk[384 + b0 + 8], a3);
            a4 = fmaf(hk, Wk[b4], a4);
        }
        // Interleaved pair layout: pair01[u][wo] at u*16+wo*2, pair23 at +128,
        // w4 at 256+u*8+wo.  Row stride 320 halfs (640 B).
        _Float16* Tr = T + (size_t)j * 320;
        int base = u * 16 + wo * 2;
        Tr[base]           = (_Float16)a0;
        Tr[base + 1]       = (_Float16)a1;
        Tr[128 + base]     = (_Float16)a2;
        Tr[128 + base + 1] = (_Float16)a3;
        Tr[256 + u * 8 + wo] = (_Float16)a4;
    }

    // geometry scatter (depends only on memset(cnt))
    int gtid = blockIdx.x * 256 + tid;
    int gsz = gridDim.x * 256;
    for (int e = gtid; e < E; e += gsz) {
        int row = ei[e];
        int col = ei[E + e];
        float ax = pos[3 * row + 0] - pos[3 * col + 0];
        float ay = pos[3 * row + 1] - pos[3 * col + 1];
        float az = pos[3 * row + 2] - pos[3 * col + 2];
        float d2 = ax * ax + ay * ay + az * az + 1e-12f;
        float invd = rsqrtf(d2);
        float dd = d2 * invd;
        int p = atomicAdd(&cnt[row], 1);
        if (p < CAP) {
            float4 r;
            r.x = ax * invd;
            r.y = ay * invd;
            r.z = az * invd;
            r.w = dd;                         // raw fp32 d -- no quantization
            srec[(size_t)row * CAP + p] = r;
        }
    }
}

// ---------------------------------------------------------------------------
// K2: one wave per node; 4 waves per block. lane = g*8+u: group g handles one
// edge per round, u indexes the input channel.  T loads pipelined 1 round deep.

#define LOADT(J, T01a, T01b, T23a, T23b, T4, U01a, U01b, U23a, U23b, U4)   \
    {                                                                      \
        const _Float16* Ar_ = T + (size_t)(J) * 320;                       \
        const _Float16* Au_ = Ar_ + u * 16;                                \
        T01a = *(const half8*)(Au_);                                       \
        T01b = *(const half8*)(Au_ + 8);                                   \
        T23a = *(const half8*)(Au_ + 128);                                 \
        T23b = *(const half8*)(Au_ + 136);                                 \
        T4   = *(const half8*)(Ar_ + 256 + u * 8);                         \
        U01a = *(const half8*)(Au_ + 320);                                 \
        U01b = *(const half8*)(Au_ + 328);                                 \
        U23a = *(const half8*)(Au_ + 448);                                 \
        U23b = *(const half8*)(Au_ + 456);                                 \
        U4   = *(const half8*)(Ar_ + 576 + u * 8);                         \
    }

__global__ __launch_bounds__(256) void tfn_node(
    const float* __restrict__ x, const float4* __restrict__ srec,
    const int* __restrict__ cnt, const _Float16* __restrict__ T,
    float* __restrict__ y, int N) {

    int wv = threadIdx.x >> 6, lane = threadIdx.x & 63;
    int n = blockIdx.x * 4 + wv;
    if (n >= N) return;                 // wave-uniform

    int g = lane >> 3;
    int u = lane & 7;
    int kc = cnt[n];
    if (kc > CAP) kc = CAP;
    const float4* recs = srec + (size_t)n * CAP;

    const float* xr = x + (size_t)n * 32;
    float xu  = xr[u];
    float xv0 = xr[8 + 3 * u + 0];
    float xv1 = xr[8 + 3 * u + 1];
    float xv2 = xr[8 + 3 * u + 2];
    _Float16 xuh = (_Float16)xu;                    // loop-invariant coefs
    _Float16 p30 = (_Float16)(xv0 * INV_S3);
    _Float16 p31 = (_Float16)(xv1 * INV_S3);
    _Float16 p32 = (_Float16)(xv2 * INV_S3);

    // V: 32 output channels (final layout). V[z]=scalar z; vec w comp k -> V[8+3w+k].
    float V[32];
#pragma unroll
    for (int z = 0; z < 32; ++z) V[z] = 0.f;

    // compute body: uses the given rec + preloaded T register set
#define COMPUTE(CUR, SLOT, J0, A01a, A01b, A23a, A23b, A4, B01a, B01b, B23a, B23b, B4) \
    if ((SLOT) < kc) {                                                     \
        float nx = (CUR).x, ny = (CUR).y, nz = (CUR).z;                    \
        float fj = (CUR).w * ((float)(TBL - 1) / DMAX);                    \
        float tf = fminf(fj - (float)(J0), 1.0f);                          \
        _Float16 th = (_Float16)tf;                                        \
        float qu = xv0 * nx + xv1 * ny + xv2 * nz;                         \
        float Y22 = 0.5f * S5 * (3.f * ny * ny - 1.f);                     \
        float Y24 = 0.5f * S15 * (nz * nz - nx * nx);                      \
        float M00 = -Y22 * INV_S30 - Y24 * INV_S10;                        \
        float M11 = 2.f * Y22 * INV_S30;                                   \
        float M22 = -Y22 * INV_S30 + Y24 * INV_S10;                        \
        float M01 = (S15 * nx * ny) * INV_S10;                             \
        float M02 = (S15 * nx * nz) * INV_S10;                             \
        float M12 = (S15 * ny * nz) * INV_S10;                             \
        float m0 = M00 * xv0 + M01 * xv1 + M02 * xv2;                      \
        float m1 = M01 * xv0 + M11 * xv1 + M12 * xv2;                      \
        float m2 = M02 * xv0 + M12 * xv1 + M22 * xv2;                      \
        half2v xq;  xq.x = xuh;  xq.y = (_Float16)qu;                      \
        half2v c0;  c0.x = (_Float16)(xu * nx);  c0.y = p30;               \
        half2v c1;  c1.x = (_Float16)(xu * ny);  c1.y = p31;               \
        half2v c2;  c2.x = (_Float16)(xu * nz);  c2.y = p32;               \
        half8 w01a, w01b, w23a, w23b, w4l;                                 \
        _Pragma("unroll")                                                  \
        for (int z = 0; z < 8; ++z) {                                      \
            w01a[z] = A01a[z] + (B01a[z] - A01a[z]) * th;                  \
            w01b[z] = A01b[z] + (B01b[z] - A01b[z]) * th;                  \
            w23a[z] = A23a[z] + (B23a[z] - A23a[z]) * th;                  \
            w23b[z] = A23b[z] + (B23b[z] - A23b[z]) * th;                  \
            w4l[z]  = A4[z]   + (B4[z]   - A4[z])   * th;                  \
        }                                                                  \
        _Pragma("unroll")                                                  \
        for (int z = 0; z < 4; ++z) {                                      \
            half2v pa; pa.x = w01a[2 * z]; pa.y = w01a[2 * z + 1];         \
            V[z] = __builtin_amdgcn_fdot2(pa, xq, V[z], false);            \
            half2v pb; pb.x = w01b[2 * z]; pb.y = w01b[2 * z + 1];         \
            V[4 + z] = __builtin_amdgcn_fdot2(pb, xq, V[4 + z], false);    \
        }                                                                  \
        _Pragma("unroll")                                                  \
        for (int z = 0; z < 4; ++z) {                                      \
            half2v pa; pa.x = w23a[2 * z]; pa.y = w23a[2 * z + 1];         \
            int b = 8 + 3 * z;                                             \
            V[b]     = __builtin_amdgcn_fdot2(pa, c0, V[b],     false);    \
            V[b + 1] = __builtin_amdgcn_fdot2(pa, c1, V[b + 1], false);    \
            V[b + 2] = __builtin_amdgcn_fdot2(pa, c2, V[b + 2], false);    \
            half2v pb; pb.x = w23b[2 * z]; pb.y = w23b[2 * z + 1];         \
            int b2 = 8 + 3 * (z + 4);                                      \
            V[b2]     = __builtin_amdgcn_fdot2(pb, c0, V[b2],     false);  \
            V[b2 + 1] = __builtin_amdgcn_fdot2(pb, c1, V[b2 + 1], false);  \
            V[b2 + 2] = __builtin_amdgcn_fdot2(pb, c2, V[b2 + 2], false);  \
        }                                                                  \
        _Pragma("unroll")                                                  \
        for (int z = 0; z < 8; ++z) {                                      \
            float we = (float)w4l[z];                                      \
            V[8 + 3 * z]  = fmaf(m0, we, V[8 + 3 * z]);                    \
            V[9 + 3 * z]  = fmaf(m1, we, V[9 + 3 * z]);                    \
            V[10 + 3 * z] = fmaf(m2, we, V[10 + 3 * z]);                   \
        }                                                                  \
    }

    int rounds = (kc + 7) >> 3;
    if (rounds > 0) {
        // ping-pong register sets; all loads speculative-but-in-bounds
        float4 rA = recs[g];
        float fjA = rA.w * ((float)(TBL - 1) / DMAX);
        int jA = max(min((int)fjA, TBL - 2), 0);
        half8 tA01a, tA01b, tA23a, tA23b, tA4, uA01a, uA01b, uA23a, uA23b, uA4;
        LOADT(jA, tA01a, tA01b, tA23a, tA23b, tA4, uA01a, uA01b, uA23a, uA23b, uA4);

        float4 rB = rA; int jB = 0;
        half8 tB01a, tB01b, tB23a, tB23b, tB4, uB01a, uB01b, uB23a, uB23b, uB4;
        if (rounds > 1) {
            rB = recs[8 + g];
            float fjB = rB.w * ((float)(TBL - 1) / DMAX);
            jB = max(min((int)fjB, TBL - 2), 0);
            LOADT(jB, tB01a, tB01b, tB23a, tB23b, tB4, uB01a, uB01b, uB23a, uB23b, uB4);
        }

        for (int rd = 0; rd < rounds; rd += 2) {
            // phase A: round rd (prefetch rd+2 rec first, reload A-set after)
            {
                float4 rN = rA;
                bool haveN = (rd + 2 < rounds);
                if (haveN) rN = recs[(rd + 2) * 8 + g];
                COMPUTE(rA, rd * 8 + g, jA,
                        tA01a, tA01b, tA23a, tA23b, tA4,
                        uA01a, uA01b, uA23a, uA23b, uA4);
                if (haveN) {
                    rA = rN;
                    float fjN = rA.w * ((float)(TBL - 1) / DMAX);
                    jA = max(min((int)fjN, TBL - 2), 0);
                    LOADT(jA, tA01a, tA01b, tA23a, tA23b, tA4,
                              uA01a, uA01b, uA23a, uA23b, uA4);
                }
            }
            // phase B: round rd+1
            if (rd + 1 < rounds) {
                float4 rM = rB;
                bool haveM = (rd + 3 < rounds);
                if (haveM) rM = recs[(rd + 3) * 8 + g];
                COMPUTE(rB, (rd + 1) * 8 + g, jB,
                        tB01a, tB01b, tB23a, tB23b, tB4,
                        uB01a, uB01b, uB23a, uB23b, uB4);
                if (haveM) {
                    rB = rM;
                    float fjM = rB.w * ((float)(TBL - 1) / DMAX);
                    jB = max(min((int)fjM, TBL - 2), 0);
                    LOADT(jB, tB01a, tB01b, tB23a, tB23b, tB4,
                              uB01a, uB01b, uB23a, uB23b, uB4);
                }
            }
        }
    }

    // Recursive-halving reduce-scatter over lane bits 4..0 (32 shfls total).
#pragma unroll
    for (int h = 16; h >= 1; h >>= 1) {
        bool hi = (lane & h) != 0;
#pragma unroll
        for (int k = 0; k < h; ++k) {
            float lo = V[k], up = V[k + h];
            float keep = hi ? up : lo;
            float send = hi ? lo : up;
            V[k] = keep + __shfl_xor(send, h, 64);
        }
    }
    V[0] += __shfl_xor(V[0], 32, 64);

    if (lane < 32) {
        float v = V[0] * 0.125f * (lane < 8 ? A0S : A1S);
        if (lane < 8) v = v / (1.0f + __expf(-v));   // silu
        y[(size_t)n * 32 + lane] = v;
    }
}

// ---------------------------------------------------------------------------
extern "C" void kernel_launch(void* const* d_in, const int* in_sizes, int n_in,
                              void* d_out, int out_size, void* d_ws, size_t ws_size,
                              hipStream_t stream) {
    const float* x   = (const float*)d_in[0];
    const float* pos = (const float*)d_in[1];
    const int*   ei  = (const int*)d_in[2];
    const float* W1  = (const float*)d_in[3];
    const float* W2  = (const float*)d_in[4];
    int N = in_sizes[1] / 3;
    int E = in_sizes[2] / 2;

    char* ws = (char*)d_ws;
    size_t off = 0;
    _Float16* T    = (_Float16*)(ws + off); off += (size_t)TBL * 320 * 2;      // 1.31 MB
    int*      cnt  = (int*)(ws + off);      off += (size_t)N * 4;              // 100 KB
    float4*   srec = (float4*)(ws + off);   off += (size_t)N * CAP * 16;       // 25.6 MB

    float* y = (float*)d_out;

    hipMemsetAsync(cnt, 0, (size_t)N * 4, stream);
    hipLaunchKernelGGL(prep_all, dim3(2048), dim3(256), 0, stream,
                       W1, W2, ei, pos, T, cnt, srec, E);
    hipLaunchKernelGGL(tfn_node, dim3((N + 3) / 4), dim3(256), 0, stream,
                       x, srec, cnt, T, y, N);
}

// Round 6
// 134.100 us; speedup vs baseline: 1.1266x; 1.1266x over previous
//
#include <hip/hip_runtime.h>
#include <hip/hip_fp16.h>

// ---------------------------------------------------------------------------
// TFN-lite layer, MI355X, round 12. Three graph nodes:
//   memset(cnt) -> prep_all(table build + geometry scatter) -> tfn_node.
//
//  R12 vs R9 (142.9 us; tfn_node 53.5 us at ~2.5 waves/SIMD residency,
//  ~1 inst / 12 cy / SIMD -- latency-dominated) and R11 (fused cooperative
//  kernel FAILED: stale cross-XCD L2 reads; dispatch boundaries are the
//  reliable invalidation points, so stay multi-kernel):
//  * tfn_node: ONE WAVE PER BLOCK (64-thr blocks, grid = N). Static limits
//    (52 VGPR, 0 LDS) allow 32 waves/CU but measured residency was ~10;
//    1-wave workgroups let the HW scheduler pack up to its WG/CU cap and
//    load-balance the Poisson degree spread at node granularity.
//    Math bit-identical to R9 -- only launch geometry changed.
//  * prep_all unchanged (2048 blocks).
// ---------------------------------------------------------------------------

#define INV_S3  0.5773502691896258f   // 1/sqrt(3)
#define A0S     0.1767766952966369f   // 1/sqrt(32)
#define A1S     0.27386127875258306f  // sqrt(3)/sqrt(40)
#define S15     3.872983346207417f    // sqrt(15)
#define S5      2.23606797749979f     // sqrt(5)
#define INV_S10 0.31622776601683794f  // 1/sqrt(10)   (cg121 normalized)
#define INV_S30 0.18257418583505536f  // 1/sqrt(30)

#define TBL   2048
#define DMAX  8.0f
#define CAP   64

typedef _Float16 half8 __attribute__((ext_vector_type(8)));
typedef _Float16 half2v __attribute__((ext_vector_type(2)));

// ---------------------------------------------------------------------------
// K1: blocks 0..511 build table rows (one wave per row j); all 2048 blocks
// then grid-stride the geometry scatter.  (unchanged from R9)
__global__ __launch_bounds__(256) void prep_all(
    const float* __restrict__ W1, const float* __restrict__ W2,
    const int* __restrict__ ei, const float* __restrict__ pos,
    _Float16* __restrict__ T, int* __restrict__ cnt,
    float4* __restrict__ srec, int E) {

    __shared__ float hs[4][64];
    int tid = threadIdx.x;
    int wv = tid >> 6, lane = tid & 63;
    int j = blockIdx.x * 4 + wv;

    float hv = 0.f;
    if (j < TBL) {
        float d = (float)j * (DMAX / (float)(TBL - 1));
        float acc = 0.f;
#pragma unroll
        for (int i = 0; i < 16; ++i) {
            float t = d - (float)i * (1.0f / 3.0f);
            float r = __expf(-4.5f * t * t);
            acc = fmaf(r, W1[i * 64 + lane], acc);
        }
        hv = fmaxf(acc, 0.f) * 0.25f;   // /sqrt(16)
    }
    hs[wv][lane] = hv;
    __syncthreads();

    if (j < TBL) {
        int u = lane >> 3, wo = lane & 7;
        int b0 = u * 16 + wo;
        int b4 = 512 + u * 8 + wo;
        float a0 = 0.f, a1 = 0.f, a2 = 0.f, a3 = 0.f, a4 = 0.f;
#pragma unroll 4
        for (int k = 0; k < 64; ++k) {
            float hk = hs[wv][k];
            const float* Wk = W2 + k * 576;
            a0 = fmaf(hk, Wk[b0]       + Wk[b0 + 8],       a0);
            a1 = fmaf(hk, Wk[128 + b0] + Wk[128 + b0 + 8], a1);
            a2 = fmaf(hk, Wk[256 + b0] + Wk[256 + b0 + 8], a2);
            a3 = fmaf(hk, Wk[384 + b0] + Wk[384 + b0 + 8], a3);
            a4 = fmaf(hk, Wk[b4], a4);
        }
        // Interleaved pair layout: pair01[u][wo] at u*16+wo*2, pair23 at +128,
        // w4 at 256+u*8+wo.  Row stride 320 halfs (640 B).
        _Float16* Tr = T + (size_t)j * 320;
        int base = u * 16 + wo * 2;
        Tr[base]           = (_Float16)a0;
        Tr[base + 1]       = (_Float16)a1;
        Tr[128 + base]     = (_Float16)a2;
        Tr[128 + base + 1] = (_Float16)a3;
        Tr[256 + u * 8 + wo] = (_Float16)a4;
    }

    // geometry scatter (depends only on memset(cnt))
    int gtid = blockIdx.x * 256 + tid;
    int gsz = gridDim.x * 256;
    for (int e = gtid; e < E; e += gsz) {
        int row = ei[e];
        int col = ei[E + e];
        float ax = pos[3 * row + 0] - pos[3 * col + 0];
        float ay = pos[3 * row + 1] - pos[3 * col + 1];
        float az = pos[3 * row + 2] - pos[3 * col + 2];
        float d2 = ax * ax + ay * ay + az * az + 1e-12f;
        float invd = rsqrtf(d2);
        float dd = d2 * invd;
        int p = atomicAdd(&cnt[row], 1);
        if (p < CAP) {
            float4 r;
            r.x = ax * invd;
            r.y = ay * invd;
            r.z = az * invd;
            r.w = dd;                         // raw fp32 d -- no quantization
            srec[(size_t)row * CAP + p] = r;
        }
    }
}

// ---------------------------------------------------------------------------
// K2: ONE WAVE PER BLOCK (64 threads); block n handles node n.
// lane = g*8+u: group g handles one edge per round, u indexes the channel.
__global__ __launch_bounds__(64) void tfn_node(
    const float* __restrict__ x, const float4* __restrict__ srec,
    const int* __restrict__ cnt, const _Float16* __restrict__ T,
    float* __restrict__ y, int N) {

    int lane = threadIdx.x & 63;
    int n = blockIdx.x;
    if (n >= N) return;

    int g = lane >> 3;
    int u = lane & 7;
    int kc = cnt[n];
    if (kc > CAP) kc = CAP;
    const float4* recs = srec + (size_t)n * CAP;

    const float* xr = x + (size_t)n * 32;
    float xu  = xr[u];
    float xv0 = xr[8 + 3 * u + 0];
    float xv1 = xr[8 + 3 * u + 1];
    float xv2 = xr[8 + 3 * u + 2];
    _Float16 xuh = (_Float16)xu;                    // loop-invariant coefs
    _Float16 p30 = (_Float16)(xv0 * INV_S3);
    _Float16 p31 = (_Float16)(xv1 * INV_S3);
    _Float16 p32 = (_Float16)(xv2 * INV_S3);

    // V: 32 output channels (final layout). V[z]=scalar z; vec w comp k -> V[8+3w+k].
    float V[32];
#pragma unroll
    for (int z = 0; z < 32; ++z) V[z] = 0.f;

    int rounds = (kc + 7) >> 3;
    float4 rec = make_float4(0.f, 0.f, 0.f, 0.f);
    if (rounds > 0) rec = recs[g];      // always-safe: CAP slots allocated
    for (int rd = 0; rd < rounds; ++rd) {
        float4 cur = rec;
        int slot = rd * 8 + g;
        if (rd + 1 < rounds) rec = recs[slot + 8];   // prefetch next round
        if (slot < kc) {
            float nx = cur.x, ny = cur.y, nz = cur.z;
            float dd = cur.w;

            float fj = dd * ((float)(TBL - 1) / DMAX);
            int j0 = (int)fj;
            j0 = min(j0, TBL - 2);
            float tf = fminf(fj - (float)j0, 1.0f);
            _Float16 th = (_Float16)tf;

            const _Float16* Ar = T + (size_t)j0 * 320;
            const _Float16* Au = Ar + u * 16;
            half8 A01a = *(const half8*)(Au);
            half8 A01b = *(const half8*)(Au + 8);
            half8 A23a = *(const half8*)(Au + 128);
            half8 A23b = *(const half8*)(Au + 136);
            half8 A4   = *(const half8*)(Ar + 256 + u * 8);
            half8 B01a = *(const half8*)(Au + 320);
            half8 B01b = *(const half8*)(Au + 328);
            half8 B23a = *(const half8*)(Au + 448);
            half8 B23b = *(const half8*)(Au + 456);
            half8 B4   = *(const half8*)(Ar + 576 + u * 8);

            // geometry (per edge, per u)
            float qu = xv0 * nx + xv1 * ny + xv2 * nz;   // (xv[u].Y1)/S3
            float Y22 = 0.5f * S5 * (3.f * ny * ny - 1.f);
            float Y24 = 0.5f * S15 * (nz * nz - nx * nx);
            float M00 = -Y22 * INV_S30 - Y24 * INV_S10;
            float M11 = 2.f * Y22 * INV_S30;
            float M22 = -Y22 * INV_S30 + Y24 * INV_S10;
            float M01 = (S15 * nx * ny) * INV_S10;
            float M02 = (S15 * nx * nz) * INV_S10;
            float M12 = (S15 * ny * nz) * INV_S10;
            float m0 = M00 * xv0 + M01 * xv1 + M02 * xv2;
            float m1 = M01 * xv0 + M11 * xv1 + M12 * xv2;
            float m2 = M02 * xv0 + M12 * xv1 + M22 * xv2;

            // packed coefficients
            half2v xq;  xq.x = xuh;  xq.y = (_Float16)qu;
            half2v c0;  c0.x = (_Float16)(xu * nx);  c0.y = p30;
            half2v c1;  c1.x = (_Float16)(xu * ny);  c1.y = p31;
            half2v c2;  c2.x = (_Float16)(xu * nz);  c2.y = p32;

            // fp16 lerp (packed): each 32-bit reg = (wA[z], wB[z]) pair
            half8 w01a, w01b, w23a, w23b, w4l;
#pragma unroll
            for (int z = 0; z < 8; ++z) {
                w01a[z] = A01a[z] + (B01a[z] - A01a[z]) * th;
                w01b[z] = A01b[z] + (B01b[z] - A01b[z]) * th;
                w23a[z] = A23a[z] + (B23a[z] - A23a[z]) * th;
                w23b[z] = A23b[z] + (B23b[z] - A23b[z]) * th;
                w4l[z]  = A4[z]   + (B4[z]   - A4[z])   * th;
            }

            // t0+t1: V[z] += w0*xu + w1*qu   (one dot2 per z)
#pragma unroll
            for (int z = 0; z < 4; ++z) {
                half2v pa; pa.x = w01a[2 * z]; pa.y = w01a[2 * z + 1];
                V[z] = __builtin_amdgcn_fdot2(pa, xq, V[z], false);
                half2v pb; pb.x = w01b[2 * z]; pb.y = w01b[2 * z + 1];
                V[4 + z] = __builtin_amdgcn_fdot2(pb, xq, V[4 + z], false);
            }

            // t2+t3: V[8+3z+k] += w2*(xu*nk) + w3*(xvk/sqrt3)
#pragma unroll
            for (int z = 0; z < 4; ++z) {
                half2v pa; pa.x = w23a[2 * z]; pa.y = w23a[2 * z + 1];
                int b = 8 + 3 * z;
                V[b]     = __builtin_amdgcn_fdot2(pa, c0, V[b],     false);
                V[b + 1] = __builtin_amdgcn_fdot2(pa, c1, V[b + 1], false);
                V[b + 2] = __builtin_amdgcn_fdot2(pa, c2, V[b + 2], false);
                half2v pb; pb.x = w23b[2 * z]; pb.y = w23b[2 * z + 1];
                int b2 = 8 + 3 * (z + 4);
                V[b2]     = __builtin_amdgcn_fdot2(pb, c0, V[b2],     false);
                V[b2 + 1] = __builtin_amdgcn_fdot2(pb, c1, V[b2 + 1], false);
                V[b2 + 2] = __builtin_amdgcn_fdot2(pb, c2, V[b2 + 2], false);
            }

            // t4: f32 (precision-critical path)
#pragma unroll
            for (int z = 0; z < 8; ++z) {
                float we = (float)w4l[z];
                V[8 + 3 * z]  = fmaf(m0, we, V[8 + 3 * z]);
                V[9 + 3 * z]  = fmaf(m1, we, V[9 + 3 * z]);
                V[10 + 3 * z] = fmaf(m2, we, V[10 + 3 * z]);
            }
        }
    }

    // Recursive-halving reduce-scatter over lane bits 4..0 (32 shfls total).
#pragma unroll
    for (int h = 16; h >= 1; h >>= 1) {
        bool hi = (lane & h) != 0;
#pragma unroll
        for (int k = 0; k < h; ++k) {
            float lo = V[k], up = V[k + h];
            float keep = hi ? up : lo;
            float send = hi ? lo : up;
            V[k] = keep + __shfl_xor(send, h, 64);
        }
    }
    V[0] += __shfl_xor(V[0], 32, 64);

    if (lane < 32) {
        float v = V[0] * 0.125f * (lane < 8 ? A0S : A1S);
        if (lane < 8) v = v / (1.0f + __expf(-v));   // silu
        y[(size_t)n * 32 + lane] = v;
    }
}

// ---------------------------------------------------------------------------
extern "C" void kernel_launch(void* const* d_in, const int* in_sizes, int n_in,
                              void* d_out, int out_size, void* d_ws, size_t ws_size,
                              hipStream_t stream) {
    const float* x   = (const float*)d_in[0];
    const float* pos = (const float*)d_in[1];
    const int*   ei  = (const int*)d_in[2];
    const float* W1  = (const float*)d_in[3];
    const float* W2  = (const float*)d_in[4];
    int N = in_sizes[1] / 3;
    int E = in_sizes[2] / 2;

    char* ws = (char*)d_ws;
    size_t off = 0;
    _Float16* T    = (_Float16*)(ws + off); off += (size_t)TBL * 320 * 2;      // 1.31 MB
    int*      cnt  = (int*)(ws + off);      off += (size_t)N * 4;              // 100 KB
    float4*   srec = (float4*)(ws + off);   off += (size_t)N * CAP * 16;       // 25.6 MB

    float* y = (float*)d_out;

    hipMemsetAsync(cnt, 0, (size_t)N * 4, stream);
    hipLaunchKernelGGL(prep_all, dim3(2048), dim3(256), 0, stream,
                       W1, W2, ei, pos, T, cnt, srec, E);
    hipLaunchKernelGGL(tfn_node, dim3(N), dim3(64), 0, stream,
                       x, srec, cnt, T, y, N);
}